// Round 8
// baseline (2332.547 us; speedup 1.0000x reference)
//
#include <hip/hip_runtime.h>

#define DI __device__ __forceinline__

typedef __attribute__((ext_vector_type(8))) short short8;
typedef __attribute__((ext_vector_type(4))) float f32x4;
typedef unsigned short u16;

// ---------- helpers ----------
DI u16 f2bf(float f) {
    union { float f; unsigned u; } v; v.f = f;
    unsigned u = v.u;
    return (u16)((u + 0x7fffu + ((u >> 16) & 1u)) >> 16);   // RNE
}
DI float bf2f(u16 h) {
    union { unsigned u; float f; } v; v.u = ((unsigned)h) << 16;
    return v.f;
}
// byte offset of 16B slot `slot` (0..3) of row `row` in a [rows][32]bf16 tile,
// XOR-swizzled: slot ^= (row>>1)&3 -> fragment reads/writes are 2-way (free).
DI int lds_off(int row, int slot) {
    return row * 64 + (((slot ^ ((row >> 1) & 3)) << 4));
}

// ---------- weight transpose+convert: Wt[N][K] bf16 = W[K][N] f32 ----------
__global__ __launch_bounds__(256) void k_wt(const float* __restrict__ W, u16* __restrict__ Wt,
                                            int K, int N, int dstL)
{
    __shared__ u16 t[32][33];
    const int tid = threadIdx.x;
    const int kt = blockIdx.x * 32, nt = blockIdx.y * 32;
    const float* Wl = W + (size_t)blockIdx.z * K * N;
    u16* Wtl = Wt + (size_t)blockIdx.z * dstL;
#pragma unroll
    for (int i = 0; i < 4; i++) {
        int k = kt + (tid >> 5) + i * 8;
        int n = nt + (tid & 31);
        float v = (n < N) ? Wl[(size_t)k * N + n] : 0.f;
        t[tid & 31][(tid >> 5) + i * 8] = f2bf(v);
    }
    __syncthreads();
#pragma unroll
    for (int i = 0; i < 4; i++) {
        int n = nt + (tid >> 5) + i * 8;
        int k = kt + (tid & 31);
        if (n < N) Wtl[(size_t)n * K + k] = t[(tid >> 5) + i * 8][tid & 31];
    }
}

// ---------- bias pack: dst[L][dstL] segment copy ----------
__global__ void k_packb(const float* __restrict__ src, int n, float* __restrict__ dst,
                        int off, int dstL)
{
    int i = blockIdx.x * 256 + threadIdx.x;
    int L = blockIdx.z;
    if (i < n) dst[(size_t)L * dstL + off + i] = src[(size_t)L * n + i];
}

// ---------- generic MFMA GEMM ----------
// AMODE: 0 = A f32; 1 = A f32 +A2; 2 = A bf16; 3 = A f32, +A2 only when n0<512
// STORE: 0 = f32 linear; 1 = bf16 value layout ((b*8+h)*8400+pix)*32+hd
template<int TM, int AMODE, int STORE, bool RELU, bool RESID>
__global__ __launch_bounds__(256) void k_gemm(
    const void* __restrict__ Ap, const float* __restrict__ A2,
    const u16* __restrict__ Bt, const float* __restrict__ bias,
    const float* __restrict__ resid, void* __restrict__ Cp,
    int M, int N, int K)
{
    constexpr int MI = TM / 32;
    __shared__ alignas(16) char Asm[TM * 64];    // TM rows x 32 bf16
    __shared__ alignas(16) char Bsm[128 * 64];   // 128 n-rows x 32 bf16
    const int tid  = threadIdx.x;
    const int lane = tid & 63;
    const int wave = tid >> 6;
    const int wr = wave >> 1, wc = wave & 1;
    const int m0 = blockIdx.x * TM, n0 = blockIdx.y * 128;
    const bool addA2 = (AMODE == 1) || (AMODE == 3 && n0 < 512);

    f32x4 acc[MI][4] = {};

    for (int kb = 0; kb < K; kb += 32) {
        if (AMODE == 2) {
            const u16* A = (const u16*)Ap;
#pragma unroll
            for (int j = 0; j < (TM * 4) / 256; j++) {
                int item = tid + j * 256;
                int r = item >> 2, ko = (item & 3) << 3;
                int grow = m0 + r; if (grow > M - 1) grow = M - 1;
                uint4 v = *(const uint4*)(A + (size_t)grow * K + kb + ko);
                *(uint4*)(Asm + lds_off(r, ko >> 3)) = v;
            }
        } else {
            constexpr int AIT = (TM * 8) / 256;
#pragma unroll
            for (int j = 0; j < AIT; j++) {
                int flat = tid + j * 256;
                int r = flat >> 3, kq = flat & 7;       // kq*4 = k offset
                int grow = m0 + r; if (grow > M - 1) grow = M - 1;
                const float* p = (const float*)Ap + (size_t)grow * K + kb + (kq << 2);
                float4 v = *(const float4*)p;
                if (addA2) {
                    float4 w = *(const float4*)(A2 + (size_t)grow * K + kb + (kq << 2));
                    v.x += w.x; v.y += w.y; v.z += w.z; v.w += w.w;
                }
                ushort4 h; h.x = f2bf(v.x); h.y = f2bf(v.y); h.z = f2bf(v.z); h.w = f2bf(v.w);
                *(ushort4*)(Asm + lds_off(r, kq >> 1) + ((kq & 1) << 3)) = h;
            }
        }
#pragma unroll
        for (int j = 0; j < 2; j++) {
            int item = tid + j * 256;               // 0..511
            int n = item >> 2, kq = item & 3;
            int gn = n0 + n; if (gn > N - 1) gn = N - 1;
            uint4 v = *(const uint4*)(Bt + (size_t)gn * K + kb + (kq << 3));
            *(uint4*)(Bsm + lds_off(n, kq)) = v;
        }
        __syncthreads();

        short8 af[MI], bfr[4];
#pragma unroll
        for (int mi = 0; mi < MI; mi++) {
            int r = wr * (TM / 2) + (mi << 4) + (lane & 15);
            af[mi] = *(const short8*)(Asm + lds_off(r, lane >> 4));
        }
#pragma unroll
        for (int ni = 0; ni < 4; ni++) {
            int c = (wc << 6) + (ni << 4) + (lane & 15);
            bfr[ni] = *(const short8*)(Bsm + lds_off(c, lane >> 4));
        }
#pragma unroll
        for (int mi = 0; mi < MI; mi++)
#pragma unroll
            for (int ni = 0; ni < 4; ni++)
                acc[mi][ni] = __builtin_amdgcn_mfma_f32_16x16x32_bf16(af[mi], bfr[ni], acc[mi][ni], 0, 0, 0);
        __syncthreads();
    }

    const int cl = lane & 15, rb = (lane >> 4) << 2;
#pragma unroll
    for (int mi = 0; mi < MI; mi++) {
#pragma unroll
        for (int ni = 0; ni < 4; ni++) {
            int col = n0 + (wc << 6) + (ni << 4) + cl;
            if (col >= N) continue;
            float bv = bias[col];
#pragma unroll
            for (int e = 0; e < 4; e++) {
                int row = m0 + wr * (TM / 2) + (mi << 4) + rb + e;
                if (row >= M) continue;
                float v = acc[mi][ni][e] + bv;
                if (RESID) v += resid[(size_t)row * N + col];
                if (RELU)  v = fmaxf(v, 0.f);
                if (STORE == 0) {
                    ((float*)Cp)[(size_t)row * N + col] = v;
                } else {
                    int b = row / 8400, pix = row - b * 8400;
                    int h = col >> 5, hd = col & 31;
                    ((u16*)Cp)[(((size_t)(b * 8 + h)) * 8400 + pix) * 32 + hd] = f2bf(v);
                }
            }
        }
    }
}

// ---------- GEMM + residual + LayerNorm fused (N=256 fixed, full row per block) ----------
// TM=16 rows/block, 4 waves each own a 64-col slice. C staged in LDS f32, per-row
// LN via 16-lane shfl reduce, output in-place-safe (block owns whole rows).
__global__ __launch_bounds__(256) void k_gemm_ln(
    const float* __restrict__ Ap, const u16* __restrict__ Bt, const float* __restrict__ bias,
    const float* __restrict__ resid, const float* __restrict__ g, const float* __restrict__ bb,
    float* __restrict__ outp, int M, int K)
{
    __shared__ alignas(16) char lds[17408];   // staging: A 1KB + B 16KB ; alias: Cf 16x264 f32
    char* Asm = lds;
    char* Bsm = lds + 1024;
    float* Cf = (float*)lds;
    const int tid = threadIdx.x;
    const int lane = tid & 63;
    const int wc = tid >> 6;
    const int c15 = lane & 15, slot = lane >> 4;
    const int m0 = blockIdx.x * 16;

    f32x4 acc[4] = {};

    for (int kb = 0; kb < K; kb += 32) {
        if (tid < 128) {
            int r = tid >> 3, kq = tid & 7;
            const float* p = Ap + (size_t)(m0 + r) * K + kb + (kq << 2);
            float4 v = *(const float4*)p;
            ushort4 h; h.x = f2bf(v.x); h.y = f2bf(v.y); h.z = f2bf(v.z); h.w = f2bf(v.w);
            *(ushort4*)(Asm + lds_off(r, kq >> 1) + ((kq & 1) << 3)) = h;
        }
#pragma unroll
        for (int j = 0; j < 4; j++) {
            int item = tid + j * 256;               // 0..1023
            int n = item >> 2, kq = item & 3;
            uint4 v = *(const uint4*)(Bt + (size_t)n * K + kb + (kq << 3));
            *(uint4*)(Bsm + lds_off(n, kq)) = v;
        }
        __syncthreads();

        short8 af = *(const short8*)(Asm + lds_off(c15, slot));
#pragma unroll
        for (int ni = 0; ni < 4; ni++) {
            int c = (wc << 6) + (ni << 4) + c15;
            short8 bfr = *(const short8*)(Bsm + lds_off(c, slot));
            acc[ni] = __builtin_amdgcn_mfma_f32_16x16x32_bf16(af, bfr, acc[ni], 0, 0, 0);
        }
        __syncthreads();
    }

    // ---- bias + residual -> Cf ----
#pragma unroll
    for (int ni = 0; ni < 4; ni++) {
        int col = (wc << 6) + (ni << 4) + c15;
        float bv = bias[col];
#pragma unroll
        for (int e = 0; e < 4; e++) {
            int rowl = (slot << 2) + e;
            float v = acc[ni][e] + bv + resid[(size_t)(m0 + rowl) * 256 + col];
            Cf[rowl * 264 + col] = v;
        }
    }
    __syncthreads();

    // ---- LN: row = tid>>4, 16 lanes per row ----
    const int row = tid >> 4, l16 = tid & 15;
    float s = 0.f, s2 = 0.f;
#pragma unroll
    for (int j = 0; j < 16; j++) {
        float x = Cf[row * 264 + l16 + j * 16];
        s += x; s2 += x * x;
    }
    s  += __shfl_xor(s, 1);  s2 += __shfl_xor(s2, 1);
    s  += __shfl_xor(s, 2);  s2 += __shfl_xor(s2, 2);
    s  += __shfl_xor(s, 4);  s2 += __shfl_xor(s2, 4);
    s  += __shfl_xor(s, 8);  s2 += __shfl_xor(s2, 8);
    float m   = s * 0.00390625f;
    float var = s2 * 0.00390625f - m * m;
    float r   = rsqrtf(var + 1e-5f);
    float* orow = outp + (size_t)(m0 + row) * 256;
#pragma unroll
    for (int j = 0; j < 4; j++) {
        int c = j * 64 + l16 * 4;
        float4 x = *(const float4*)(Cf + row * 264 + c);
        float4 gv = *(const float4*)(g + c);
        float4 bv = *(const float4*)(bb + c);
        float4 o;
        o.x = (x.x - m) * r * gv.x + bv.x;
        o.y = (x.y - m) * r * gv.y + bv.y;
        o.z = (x.z - m) * r * gv.z + bv.z;
        o.w = (x.w - m) * r * gv.w + bv.w;
        *(float4*)(orow + c) = o;
    }
}

// ---------- MHA v3: MFMA flash attention ----------
// grid (5 qtiles of 64, 128 bh); 256 thr = 4 waves; wave owns 16 q rows.
// qkv [4800][768]: Q cols h*32, K cols 256+h*32, V cols 512+h*32; out [4800][256].
// LDS union: P[64][328]bf16 (aliases K[304][40]bf16) + Vt[32][328]bf16 = 62976 B.
__global__ __launch_bounds__(256) void k_mha3(const float* __restrict__ qkv, float* __restrict__ outp)
{
    __shared__ alignas(16) char lds[62976];
    u16* Ksh = (u16*)lds;              // [304][40] (k rows, d cols), dead after QK
    u16* Psh = (u16*)lds;              // [64][328]  (q rows, k cols), aliases Ksh
    u16* Vt  = (u16*)(lds + 41984);    // [32][328]  (d rows, k cols)

    const int q0 = blockIdx.x * 64;
    const int bh = blockIdx.y;
    const int h = bh & 7, b = bh >> 3;
    const int tid = threadIdx.x;
    const int wv = tid >> 6, l = tid & 63;
    const int c15 = l & 15, slot = l >> 4;
    const float scale = 0.17677669529663687f;  // 1/sqrt(32)

    // ---- stage K [304 rows][32 d] bf16 (rows>=300 zero) ----
    for (int item = tid; item < 304 * 8; item += 256) {
        int kk = item >> 3, dq = (item & 7) << 2;
        ushort4 hv = {0, 0, 0, 0};
        if (kk < 300) {
            float4 v = *(const float4*)(qkv + (size_t)(b * 300 + kk) * 768 + 256 + h * 32 + dq);
            hv.x = f2bf(v.x); hv.y = f2bf(v.y); hv.z = f2bf(v.z); hv.w = f2bf(v.w);
        }
        *(ushort4*)(Ksh + kk * 40 + dq) = hv;
    }
    // ---- stage V transposed: Vt[d][k], k in [0,320) (k>=300 zero) ----
    for (int item = tid; item < 320 * 8; item += 256) {
        int kk = item >> 3, dq = (item & 7) << 2;
        float4 v = {0, 0, 0, 0};
        if (kk < 300)
            v = *(const float4*)(qkv + (size_t)(b * 300 + kk) * 768 + 512 + h * 32 + dq);
        Vt[(dq + 0) * 328 + kk] = f2bf(v.x);
        Vt[(dq + 1) * 328 + kk] = f2bf(v.y);
        Vt[(dq + 2) * 328 + kk] = f2bf(v.z);
        Vt[(dq + 3) * 328 + kk] = f2bf(v.w);
    }
    // ---- Q A-fragment from global (scaled) ----
    short8 qf;
    {
        int qrow = q0 + 16 * wv + c15; if (qrow > 299) qrow = 299;
        const float* qs = qkv + (size_t)(b * 300 + qrow) * 768 + h * 32 + (slot << 3);
        float4 a0 = *(const float4*)qs, a1 = *(const float4*)(qs + 4);
        qf[0] = (short)f2bf(a0.x * scale); qf[1] = (short)f2bf(a0.y * scale);
        qf[2] = (short)f2bf(a0.z * scale); qf[3] = (short)f2bf(a0.w * scale);
        qf[4] = (short)f2bf(a1.x * scale); qf[5] = (short)f2bf(a1.y * scale);
        qf[6] = (short)f2bf(a1.z * scale); qf[7] = (short)f2bf(a1.w * scale);
    }
    __syncthreads();

    // ---- QK^T: 19 k-tiles of 16, scores in registers ----
    f32x4 sc[19];
    const f32x4 zero4 = {0.f, 0.f, 0.f, 0.f};
#pragma unroll
    for (int t = 0; t < 19; t++) {
        short8 kf = *(const short8*)(Ksh + (16 * t + c15) * 40 + (slot << 3));
        sc[t] = __builtin_amdgcn_mfma_f32_16x16x32_bf16(qf, kf, zero4, 0, 0, 0);
    }
    __syncthreads();   // K dead everywhere; P may now overwrite it

    // ---- in-register softmax; P -> LDS bf16 ----
    float linv[4];
    const int prow0 = 16 * wv + (slot << 2);
#pragma unroll
    for (int e = 0; e < 4; e++) {
        float mm = -1e30f;
#pragma unroll
        for (int t = 0; t < 18; t++) mm = fmaxf(mm, sc[t][e]);
        if (c15 < 12) mm = fmaxf(mm, sc[18][e]);
        mm = fmaxf(mm, __shfl_xor(mm, 1));
        mm = fmaxf(mm, __shfl_xor(mm, 2));
        mm = fmaxf(mm, __shfl_xor(mm, 4));
        mm = fmaxf(mm, __shfl_xor(mm, 8));
        float ls = 0.f;
#pragma unroll
        for (int t = 0; t < 19; t++) {
            float p = __expf(sc[t][e] - mm);
            if (t == 18 && c15 >= 12) p = 0.f;
            ls += p;
            Psh[(prow0 + e) * 328 + 16 * t + c15] = f2bf(p);
        }
        ls += __shfl_xor(ls, 1);
        ls += __shfl_xor(ls, 2);
        ls += __shfl_xor(ls, 4);
        ls += __shfl_xor(ls, 8);
        linv[e] = 1.f / ls;
    }
    // zero P cols 304..319 of this wave's rows (PV k-steps reach 319)
    {
        int r = 16 * wv + (l >> 2);
        int c = 304 + ((l & 3) << 2);
        Psh[r * 328 + c + 0] = 0; Psh[r * 328 + c + 1] = 0;
        Psh[r * 328 + c + 2] = 0; Psh[r * 328 + c + 3] = 0;
    }

    // ---- PV: O[16q x 32d] per wave, 10 k-steps of 32 ----
#pragma unroll
    for (int df = 0; df < 2; df++) {
        f32x4 o = zero4;
#pragma unroll
        for (int t = 0; t < 10; t++) {
            short8 pf = *(const short8*)(Psh + (16 * wv + c15) * 328 + 32 * t + (slot << 3));
            short8 vf = *(const short8*)(Vt + (16 * df + c15) * 328 + 32 * t + (slot << 3));
            o = __builtin_amdgcn_mfma_f32_16x16x32_bf16(pf, vf, o, 0, 0, 0);
        }
#pragma unroll
        for (int e = 0; e < 4; e++) {
            int qrow = q0 + prow0 + e;
            if (qrow < 300)
                outp[(size_t)(b * 300 + qrow) * 256 + h * 32 + 16 * df + c15] = o[e] * linv[e];
        }
    }
}

// ---------- deformable sampling with inline aw-softmax ----------
__global__ __launch_bounds__(256) void k_msda(const u16* __restrict__ value, const float* __restrict__ offaw,
                                              const float* __restrict__ ref, float* __restrict__ samp)
{
    int it = blockIdx.x * 8 + (threadIdx.x >> 5);
    int d  = threadIdx.x & 31;
    int h = it & 7, row = it >> 3;
    int b = row / 300;
    const float* rf = ref + (size_t)row * 4;
    float rx = rf[0], ry = rf[1];
    float rw = rf[2] * 0.125f, rh = rf[3] * 0.125f;   // /P * 0.5
    const float* offp = offaw + (size_t)row * 288 + h * 24;
    const float* awp  = offaw + (size_t)row * 288 + 192 + h * 12;
    // inline softmax over 12 (redundant per lane, VALU-cheap)
    float aw[12];
    {
        float mm = awp[0];
#pragma unroll
        for (int i = 1; i < 12; i++) mm = fmaxf(mm, awp[i]);
        float ssum = 0.f;
#pragma unroll
        for (int i = 0; i < 12; i++) { aw[i] = __expf(awp[i] - mm); ssum += aw[i]; }
        float inv = 1.f / ssum;
#pragma unroll
        for (int i = 0; i < 12; i++) aw[i] *= inv;
    }
    const u16* vb = value + ((size_t)(b * 8 + h)) * 8400 * 32 + d;
    const int HW[3] = {80, 40, 20};
    const int st[3] = {0, 6400, 8000};
    float acc = 0.f;
#pragma unroll
    for (int lv = 0; lv < 3; lv++) {
        int Wl = HW[lv], Hl = HW[lv];
        float Wf = (float)Wl, Hf = (float)Hl;
#pragma unroll
        for (int p = 0; p < 4; p++) {
            float a = aw[lv * 4 + p];
            float x = (rx + offp[lv*8 + p*2]     * rw) * Wf - 0.5f;
            float y = (ry + offp[lv*8 + p*2 + 1] * rh) * Hf - 0.5f;
            float xf = floorf(x), yf = floorf(y);
            float wx = x - xf, wy = y - yf;
            int x0 = (int)xf, y0 = (int)yf;
#pragma unroll
            for (int t = 0; t < 4; t++) {
                int xx = x0 + (t & 1), yy = y0 + (t >> 1);
                if (xx >= 0 && xx < Wl && yy >= 0 && yy < Hl) {
                    float w = ((t & 1) ? wx : 1.f - wx) * ((t >> 1) ? wy : 1.f - wy);
                    acc += a * w * bf2f(vb[(size_t)(st[lv] + yy * Wl + xx) * 32]);
                }
            }
        }
    }
    samp[(size_t)row * 256 + h * 32 + d] = acc;
}

// ---------- qpe hidden: relu(ref(4) @ W1(4,512) + b1) ----------
__global__ void k_qpe_hidden(const float* __restrict__ ref, const float* __restrict__ W1,
                             const float* __restrict__ b1, float* __restrict__ hid)
{
    int idx = blockIdx.x * 256 + threadIdx.x;
    if (idx >= 4800 * 512) return;
    int row = idx >> 9, col = idx & 511;
    const float* r = ref + (size_t)row * 4;
    float v = b1[col] + r[0]*W1[col] + r[1]*W1[512+col] + r[2]*W1[1024+col] + r[3]*W1[1536+col];
    hid[idx] = fmaxf(v, 0.f);
}

// ---------- bbox tail ----------
__global__ __launch_bounds__(64) void k_bb3(const float* __restrict__ bb2, const float* __restrict__ W3,
                                            const float* __restrict__ b3, float* __restrict__ ref)
{
    int row = blockIdx.x;
    int lane = threadIdx.x;
    const float* xr = bb2 + (size_t)row * 256;
    float s0 = 0, s1 = 0, s2 = 0, s3 = 0;
#pragma unroll
    for (int k = lane; k < 256; k += 64) {
        float xv = xr[k];
        float4 w = *(const float4*)(W3 + k * 4);
        s0 += xv * w.x; s1 += xv * w.y; s2 += xv * w.z; s3 += xv * w.w;
    }
#pragma unroll
    for (int off = 32; off >= 1; off >>= 1) {
        s0 += __shfl_xor(s0, off); s1 += __shfl_xor(s1, off);
        s2 += __shfl_xor(s2, off); s3 += __shfl_xor(s3, off);
    }
    if (lane == 0) {
        float sv[4] = {s0, s1, s2, s3};
        float* rr = ref + (size_t)row * 4;
#pragma unroll
        for (int j = 0; j < 4; j++) {
            float v = sv[j] + b3[j];
            float o = rr[j];
            o = fminf(fmaxf(o, 1e-5f), 1.f - 1e-5f);
            float inv = logf(o / (1.f - o));
            rr[j] = 1.f / (1.f + expf(-(v + inv)));
        }
    }
}

// ---------- small utility kernels ----------
__global__ void k_cvt_bf16(const float* __restrict__ in, u16* __restrict__ out, int n4)
{
    int i = blockIdx.x * 256 + threadIdx.x;
    if (i >= n4) return;
    float4 v = ((const float4*)in)[i];
    ushort4 h; h.x = f2bf(v.x); h.y = f2bf(v.y); h.z = f2bf(v.z); h.w = f2bf(v.w);
    ((ushort4*)out)[i] = h;
}
__global__ void k_copy4(const float* __restrict__ in, float* __restrict__ out, int n4)
{
    int i = blockIdx.x * 256 + threadIdx.x;
    if (i >= n4) return;
    ((float4*)out)[i] = ((const float4*)in)[i];
}
__global__ void k_sigmoid(const float* __restrict__ in, float* __restrict__ out, int n)
{
    int i = blockIdx.x * 256 + threadIdx.x;
    if (i >= n) return;
    out[i] = 1.f / (1.f + __expf(-in[i]));
}

// ---------- host-side launch helpers ----------
static inline dim3 g32(int M, int N) { return dim3((M + 31) / 32, (N + 127) / 128); }

static void gemm_plain(const float* A, const u16* Bt, const float* bias, float* C,
                       int M, int N, int K, hipStream_t s) {
    k_gemm<32, 0, 0, false, false><<<g32(M, N), 256, 0, s>>>((const void*)A, nullptr, Bt, bias, nullptr, (void*)C, M, N, K);
}
static void gemm_add(const float* A, const float* A2, const u16* Bt, const float* bias, float* C,
                     int M, int N, int K, hipStream_t s) {
    k_gemm<32, 1, 0, false, false><<<g32(M, N), 256, 0, s>>>((const void*)A, A2, Bt, bias, nullptr, (void*)C, M, N, K);
}
static void gemm_qkv(const float* A, const float* A2, const u16* Bt, const float* bias, float* C,
                     hipStream_t s) {
    k_gemm<32, 3, 0, false, false><<<g32(4800, 768), 256, 0, s>>>((const void*)A, A2, Bt, bias, nullptr, (void*)C, 4800, 768, 256);
}
static void gemm_relu(const float* A, const u16* Bt, const float* bias, float* C,
                      int M, int N, int K, hipStream_t s) {
    k_gemm<32, 0, 0, true, false><<<g32(M, N), 256, 0, s>>>((const void*)A, nullptr, Bt, bias, nullptr, (void*)C, M, N, K);
}
static void gemm_value(const u16* A, const u16* Bt, const float* bias, u16* C, hipStream_t s) {
    k_gemm<128, 2, 1, false, false><<<dim3(1050, 2), 256, 0, s>>>((const void*)A, nullptr, Bt, bias, nullptr, (void*)C, 134400, 256, 256);
}
static void gemm_ln(const float* A, const u16* Bt, const float* bias, const float* resid,
                    const float* g, const float* bb, float* out, int K, hipStream_t s) {
    k_gemm_ln<<<300, 256, 0, s>>>(A, Bt, bias, resid, g, bb, out, 4800, K);
}

extern "C" void kernel_launch(void* const* d_in, const int* in_sizes, int n_in,
                              void* d_out, int out_size, void* d_ws, size_t ws_size,
                              hipStream_t stream)
{
    const float* tgt       = (const float*)d_in[0];
    const float* ref_unact = (const float*)d_in[1];
    const float* memory    = (const float*)d_in[2];
    const float* self_Wq = (const float*)d_in[4];
    const float* self_bq = (const float*)d_in[5];
    const float* self_Wk = (const float*)d_in[6];
    const float* self_bk = (const float*)d_in[7];
    const float* self_Wv = (const float*)d_in[8];
    const float* self_bv = (const float*)d_in[9];
    const float* self_Wo = (const float*)d_in[10];
    const float* self_bo = (const float*)d_in[11];
    const float* ln1_g = (const float*)d_in[12];
    const float* ln1_b = (const float*)d_in[13];
    const float* ln2_g = (const float*)d_in[14];
    const float* ln2_b = (const float*)d_in[15];
    const float* ln3_g = (const float*)d_in[16];
    const float* ln3_b = (const float*)d_in[17];
    const float* off_W = (const float*)d_in[18];
    const float* off_b = (const float*)d_in[19];
    const float* aw_W  = (const float*)d_in[20];
    const float* aw_b  = (const float*)d_in[21];
    const float* val_W = (const float*)d_in[22];
    const float* val_b = (const float*)d_in[23];
    const float* out_W = (const float*)d_in[24];
    const float* out_b = (const float*)d_in[25];
    const float* ffn_W1 = (const float*)d_in[26];
    const float* ffn_b1 = (const float*)d_in[27];
    const float* ffn_W2 = (const float*)d_in[28];
    const float* ffn_b2 = (const float*)d_in[29];
    const float* qph_W1 = (const float*)d_in[30];
    const float* qph_b1 = (const float*)d_in[31];
    const float* qph_W2 = (const float*)d_in[32];
    const float* qph_b2 = (const float*)d_in[33];
    const float* bb_W1 = (const float*)d_in[34];
    const float* bb_b1 = (const float*)d_in[35];
    const float* bb_W2 = (const float*)d_in[36];
    const float* bb_b2 = (const float*)d_in[37];
    const float* bb_W3 = (const float*)d_in[38];
    const float* bb_b3 = (const float*)d_in[39];
    const float* sc_W  = (const float*)d_in[40];
    const float* sc_b  = (const float*)d_in[41];
    float* out_f = (float*)d_out;

    // ---- workspace layout (bytes) ----
    char* w = (char*)d_ws;
    u16* mem_bf = (u16*)(w + 0);                // 68,812,800 B
    u16* value  = (u16*)(w + 68812800);         // 68,812,800 B
    const size_t F0 = 137625600;
    float* ws_out   = (float*)(w + F0);                 // 4800x256
    float* ws_qpe   = (float*)(w + F0 +  4915200);      // 4800x256
    float* ws_hid   = (float*)(w + F0 +  9830400);      // 4800x512
    float* ws_qkv   = (float*)(w + F0 + 19660800);      // 4800x768 (Q|K|V)
    float* ws_attn  = (float*)(w + F0 + 34406400);      // 4800x256
    float* ws_offaw = (float*)(w + F0 + 39321600);      // 4800x288 (off|aw raw)
    float* ws_samp  = (float*)(w + F0 + 44851200);      // 4800x256
    float* ws_ffn   = (float*)(w + F0 + 49766400);      // 4800x1024
    float* ws_bb1   = (float*)(w + F0 + 69427200);      // 4800x256
    float* ws_bb2   = (float*)(w + F0 + 74342400);      // 4800x256
    float* ws_ref   = (float*)(w + F0 + 79257600);      // 4800x4
    float* bias_qkv = (float*)(w + F0 + 79334400);      // 6x768
    float* bias_oa  = (float*)(w + F0 + 79352832);      // 6x288
    // ---- bf16 transposed weights (u16 elements), 16B-aligned ----
    u16* wt = (u16*)(w + F0 + 79360000);
    u16* wt_qkv   = wt;                    // 6 x 768x256
    u16* wt_o     = wt_qkv   + 1179648;    // 6 x 65536
    u16* wt_offaw = wt_o     + 393216;     // 6 x 288x256
    u16* wt_val   = wt_offaw + 442368;
    u16* wt_out   = wt_val   + 393216;
    u16* wt_f1    = wt_out   + 393216;     // 6 x 262144
    u16* wt_f2    = wt_f1    + 1572864;
    u16* wt_b1    = wt_f2    + 1572864;
    u16* wt_b2    = wt_b1    + 393216;
    u16* wt_qp2   = wt_b2    + 393216;     // 131072
    u16* wt_sc    = wt_qp2   + 131072;     // 20480

    // ---- init: weight transposes + bias packs ----
    k_wt<<<dim3(8, 8, 6),  256, 0, stream>>>(self_Wq, wt_qkv,           256, 256, 196608);
    k_wt<<<dim3(8, 8, 6),  256, 0, stream>>>(self_Wk, wt_qkv + 65536,   256, 256, 196608);
    k_wt<<<dim3(8, 8, 6),  256, 0, stream>>>(self_Wv, wt_qkv + 131072,  256, 256, 196608);
    k_wt<<<dim3(8, 8, 6),  256, 0, stream>>>(self_Wo, wt_o,             256, 256, 65536);
    k_wt<<<dim3(8, 6, 6),  256, 0, stream>>>(off_W,   wt_offaw,         256, 192, 73728);
    k_wt<<<dim3(8, 3, 6),  256, 0, stream>>>(aw_W,    wt_offaw + 49152, 256, 96,  73728);
    k_wt<<<dim3(8, 8, 6),  256, 0, stream>>>(val_W,   wt_val,           256, 256, 65536);
    k_wt<<<dim3(8, 8, 6),  256, 0, stream>>>(out_W,   wt_out,           256, 256, 65536);
    k_wt<<<dim3(8, 32, 6), 256, 0, stream>>>(ffn_W1,  wt_f1,            256, 1024, 262144);
    k_wt<<<dim3(32, 8, 6), 256, 0, stream>>>(ffn_W2,  wt_f2,            1024, 256, 262144);
    k_wt<<<dim3(8, 8, 6),  256, 0, stream>>>(bb_W1,   wt_b1,            256, 256, 65536);
    k_wt<<<dim3(8, 8, 6),  256, 0, stream>>>(bb_W2,   wt_b2,            256, 256, 65536);
    k_wt<<<dim3(16, 8, 1), 256, 0, stream>>>(qph_W2,  wt_qp2,           512, 256, 131072);
    k_wt<<<dim3(8, 3, 1),  256, 0, stream>>>(sc_W + (size_t)5 * 20480, wt_sc, 256, 80, 20480);
    k_packb<<<dim3(1, 1, 6), 256, 0, stream>>>(self_bq, 256, bias_qkv, 0,   768);
    k_packb<<<dim3(1, 1, 6), 256, 0, stream>>>(self_bk, 256, bias_qkv, 256, 768);
    k_packb<<<dim3(1, 1, 6), 256, 0, stream>>>(self_bv, 256, bias_qkv, 512, 768);
    k_packb<<<dim3(1, 1, 6), 256, 0, stream>>>(off_b,   192, bias_oa,  0,   288);
    k_packb<<<dim3(1, 1, 6), 256, 0, stream>>>(aw_b,     96, bias_oa,  192, 288);

    k_cvt_bf16<<<33600, 256, 0, stream>>>(memory, mem_bf, 8601600);
    k_copy4   <<<1200,  256, 0, stream>>>(tgt, ws_out, 307200);
    k_sigmoid <<<75,    256, 0, stream>>>(ref_unact, ws_ref, 19200);

    for (int l = 0; l < 6; l++) {
        // qpe = relu(ref @ qph_W1 + b1) @ qph_W2 + b2
        k_qpe_hidden<<<9600, 256, 0, stream>>>(ws_ref, qph_W1, qph_b1, ws_hid);
        gemm_plain(ws_hid, wt_qp2, qph_b2, ws_qpe, 4800, 256, 512, stream);

        // self-attention: fused QKV projection (qpe added only to Q,K tiles)
        gemm_qkv(ws_out, ws_qpe, wt_qkv + (size_t)l * 196608, bias_qkv + l * 768, ws_qkv, stream);
        k_mha3<<<dim3(5, 128), 256, 0, stream>>>(ws_qkv, ws_attn);
        gemm_ln(ws_attn, wt_o + (size_t)l * 65536, self_bo + l * 256, ws_out,
                ln1_g + l * 256, ln1_b + l * 256, ws_out, 256, stream);

        // value projection (bf16 A, bf16 out, (b,h,pix,hd) layout)
        gemm_value(mem_bf, wt_val + (size_t)l * 65536, val_b + l * 256, value, stream);

        // deformable attention (fused off|aw projection, softmax inside msda)
        gemm_add(ws_out, ws_qpe, wt_offaw + (size_t)l * 73728, bias_oa + l * 288, ws_offaw, 4800, 288, 256, stream);
        k_msda<<<4800, 256, 0, stream>>>(value, ws_offaw, ws_ref, ws_samp);
        gemm_ln(ws_samp, wt_out + (size_t)l * 65536, out_b + l * 256, ws_out,
                ln2_g + l * 256, ln2_b + l * 256, ws_out, 256, stream);

        // FFN
        gemm_relu(ws_out, wt_f1 + (size_t)l * 262144, ffn_b1 + l * 1024, ws_ffn, 4800, 1024, 256, stream);
        gemm_ln(ws_ffn, wt_f2 + (size_t)l * 262144, ffn_b2 + l * 256, ws_out,
                ln3_g + l * 256, ln3_b + l * 256, ws_out, 1024, stream);

        // bbox head + ref update
        gemm_relu(ws_out, wt_b1 + (size_t)l * 65536, bb_b1 + l * 256, ws_bb1, 4800, 256, 256, stream);
        gemm_relu(ws_bb1, wt_b2 + (size_t)l * 65536, bb_b2 + l * 256, ws_bb2, 4800, 256, 256, stream);
        k_bb3<<<4800, 64, 0, stream>>>(ws_bb2, bb_W3 + (size_t)l * 1024, bb_b3 + l * 4, ws_ref);
    }

    // outputs: ref (19200 f32) then logits (4800x80 f32)
    k_copy4<<<19, 256, 0, stream>>>(ws_ref, out_f, 4800);
    gemm_plain(ws_out, wt_sc, sc_b + 5 * 80, out_f + 19200, 4800, 80, 256, stream);
}

// Round 9
// 2194.689 us; speedup vs baseline: 1.0628x; 1.0628x over previous
//
#include <hip/hip_runtime.h>

#define DI __device__ __forceinline__

typedef __attribute__((ext_vector_type(8))) short short8;
typedef __attribute__((ext_vector_type(4))) float f32x4;
typedef unsigned short u16;

// ---------- helpers ----------
DI u16 f2bf(float f) {
    union { float f; unsigned u; } v; v.f = f;
    unsigned u = v.u;
    return (u16)((u + 0x7fffu + ((u >> 16) & 1u)) >> 16);   // RNE
}
DI float bf2f(u16 h) {
    union { unsigned u; float f; } v; v.u = ((unsigned)h) << 16;
    return v.f;
}
// byte offset of 16B slot `slot` (0..3) of row `row` in a [rows][32]bf16 tile,
// XOR-swizzled: slot ^= (row>>1)&3 -> fragment reads/writes are 2-way (free).
DI int lds_off(int row, int slot) {
    return row * 64 + (((slot ^ ((row >> 1) & 3)) << 4));
}

// ---------- weight transpose+convert: Wt[N][K] bf16 = W[K][N] f32 ----------
__global__ __launch_bounds__(256) void k_wt(const float* __restrict__ W, u16* __restrict__ Wt,
                                            int K, int N, int dstL)
{
    __shared__ u16 t[32][33];
    const int tid = threadIdx.x;
    const int kt = blockIdx.x * 32, nt = blockIdx.y * 32;
    const float* Wl = W + (size_t)blockIdx.z * K * N;
    u16* Wtl = Wt + (size_t)blockIdx.z * dstL;
#pragma unroll
    for (int i = 0; i < 4; i++) {
        int k = kt + (tid >> 5) + i * 8;
        int n = nt + (tid & 31);
        float v = (n < N) ? Wl[(size_t)k * N + n] : 0.f;
        t[tid & 31][(tid >> 5) + i * 8] = f2bf(v);
    }
    __syncthreads();
#pragma unroll
    for (int i = 0; i < 4; i++) {
        int n = nt + (tid >> 5) + i * 8;
        int k = kt + (tid & 31);
        if (n < N) Wtl[(size_t)n * K + k] = t[(tid >> 5) + i * 8][tid & 31];
    }
}

// ---------- bias pack: dst[L][dstL] segment copy ----------
__global__ void k_packb(const float* __restrict__ src, int n, float* __restrict__ dst,
                        int off, int dstL)
{
    int i = blockIdx.x * 256 + threadIdx.x;
    int L = blockIdx.z;
    if (i < n) dst[(size_t)L * dstL + off + i] = src[(size_t)L * n + i];
}

// ---------- generic MFMA GEMM ----------
// AMODE: 0 = A f32; 1 = A f32 +A2; 2 = A bf16; 3 = A f32, +A2 only when n0<512
// STORE: 0 = f32 linear; 1 = bf16 value layout ((b*8+h)*8400+pix)*32+hd
template<int TM, int AMODE, int STORE, bool RELU, bool RESID>
__global__ __launch_bounds__(256) void k_gemm(
    const void* __restrict__ Ap, const float* __restrict__ A2,
    const u16* __restrict__ Bt, const float* __restrict__ bias,
    const float* __restrict__ resid, void* __restrict__ Cp,
    int M, int N, int K)
{
    constexpr int MI = TM / 32;
    __shared__ alignas(16) char Asm[TM * 64];    // TM rows x 32 bf16
    __shared__ alignas(16) char Bsm[128 * 64];   // 128 n-rows x 32 bf16
    const int tid  = threadIdx.x;
    const int lane = tid & 63;
    const int wave = tid >> 6;
    const int wr = wave >> 1, wc = wave & 1;
    const int m0 = blockIdx.x * TM, n0 = blockIdx.y * 128;
    const bool addA2 = (AMODE == 1) || (AMODE == 3 && n0 < 512);

    f32x4 acc[MI][4] = {};

    for (int kb = 0; kb < K; kb += 32) {
        if (AMODE == 2) {
            const u16* A = (const u16*)Ap;
#pragma unroll
            for (int j = 0; j < (TM * 4) / 256; j++) {
                int item = tid + j * 256;
                int r = item >> 2, ko = (item & 3) << 3;
                int grow = m0 + r; if (grow > M - 1) grow = M - 1;
                uint4 v = *(const uint4*)(A + (size_t)grow * K + kb + ko);
                *(uint4*)(Asm + lds_off(r, ko >> 3)) = v;
            }
        } else {
            constexpr int AIT = (TM * 8) / 256;
#pragma unroll
            for (int j = 0; j < AIT; j++) {
                int flat = tid + j * 256;
                int r = flat >> 3, kq = flat & 7;       // kq*4 = k offset
                int grow = m0 + r; if (grow > M - 1) grow = M - 1;
                const float* p = (const float*)Ap + (size_t)grow * K + kb + (kq << 2);
                float4 v = *(const float4*)p;
                if (addA2) {
                    float4 w = *(const float4*)(A2 + (size_t)grow * K + kb + (kq << 2));
                    v.x += w.x; v.y += w.y; v.z += w.z; v.w += w.w;
                }
                ushort4 h; h.x = f2bf(v.x); h.y = f2bf(v.y); h.z = f2bf(v.z); h.w = f2bf(v.w);
                *(ushort4*)(Asm + lds_off(r, kq >> 1) + ((kq & 1) << 3)) = h;
            }
        }
#pragma unroll
        for (int j = 0; j < 2; j++) {
            int item = tid + j * 256;               // 0..511
            int n = item >> 2, kq = item & 3;
            int gn = n0 + n; if (gn > N - 1) gn = N - 1;
            uint4 v = *(const uint4*)(Bt + (size_t)gn * K + kb + (kq << 3));
            *(uint4*)(Bsm + lds_off(n, kq)) = v;
        }
        __syncthreads();

        short8 af[MI], bfr[4];
#pragma unroll
        for (int mi = 0; mi < MI; mi++) {
            int r = wr * (TM / 2) + (mi << 4) + (lane & 15);
            af[mi] = *(const short8*)(Asm + lds_off(r, lane >> 4));
        }
#pragma unroll
        for (int ni = 0; ni < 4; ni++) {
            int c = (wc << 6) + (ni << 4) + (lane & 15);
            bfr[ni] = *(const short8*)(Bsm + lds_off(c, lane >> 4));
        }
#pragma unroll
        for (int mi = 0; mi < MI; mi++)
#pragma unroll
            for (int ni = 0; ni < 4; ni++)
                acc[mi][ni] = __builtin_amdgcn_mfma_f32_16x16x32_bf16(af[mi], bfr[ni], acc[mi][ni], 0, 0, 0);
        __syncthreads();
    }

    const int cl = lane & 15, rb = (lane >> 4) << 2;
#pragma unroll
    for (int mi = 0; mi < MI; mi++) {
#pragma unroll
        for (int ni = 0; ni < 4; ni++) {
            int col = n0 + (wc << 6) + (ni << 4) + cl;
            if (col >= N) continue;
            float bv = bias[col];
#pragma unroll
            for (int e = 0; e < 4; e++) {
                int row = m0 + wr * (TM / 2) + (mi << 4) + rb + e;
                if (row >= M) continue;
                float v = acc[mi][ni][e] + bv;
                if (RESID) v += resid[(size_t)row * N + col];
                if (RELU)  v = fmaxf(v, 0.f);
                if (STORE == 0) {
                    ((float*)Cp)[(size_t)row * N + col] = v;
                } else {
                    int b = row / 8400, pix = row - b * 8400;
                    int h = col >> 5, hd = col & 31;
                    ((u16*)Cp)[(((size_t)(b * 8 + h)) * 8400 + pix) * 32 + hd] = f2bf(v);
                }
            }
        }
    }
}

// ---------- MHA v3: MFMA flash attention ----------
// grid (5 qtiles of 64, 128 bh); 256 thr = 4 waves; wave owns 16 q rows.
// qkv [4800][768]: Q cols h*32, K cols 256+h*32, V cols 512+h*32; out [4800][256].
// LDS union: P[64][328]bf16 (aliases K[304][40]bf16) + Vt[32][328]bf16 = 62976 B.
__global__ __launch_bounds__(256) void k_mha3(const float* __restrict__ qkv, float* __restrict__ outp)
{
    __shared__ alignas(16) char lds[62976];
    u16* Ksh = (u16*)lds;              // [304][40] (k rows, d cols), dead after QK
    u16* Psh = (u16*)lds;              // [64][328]  (q rows, k cols), aliases Ksh
    u16* Vt  = (u16*)(lds + 41984);    // [32][328]  (d rows, k cols)

    const int q0 = blockIdx.x * 64;
    const int bh = blockIdx.y;
    const int h = bh & 7, b = bh >> 3;
    const int tid = threadIdx.x;
    const int wv = tid >> 6, l = tid & 63;
    const int c15 = l & 15, slot = l >> 4;
    const float scale = 0.17677669529663687f;  // 1/sqrt(32)

    // ---- stage K [304 rows][32 d] bf16 (rows>=300 zero) ----
    for (int item = tid; item < 304 * 8; item += 256) {
        int kk = item >> 3, dq = (item & 7) << 2;
        ushort4 hv = {0, 0, 0, 0};
        if (kk < 300) {
            float4 v = *(const float4*)(qkv + (size_t)(b * 300 + kk) * 768 + 256 + h * 32 + dq);
            hv.x = f2bf(v.x); hv.y = f2bf(v.y); hv.z = f2bf(v.z); hv.w = f2bf(v.w);
        }
        *(ushort4*)(Ksh + kk * 40 + dq) = hv;
    }
    // ---- stage V transposed: Vt[d][k], k in [0,320) (k>=300 zero) ----
    for (int item = tid; item < 320 * 8; item += 256) {
        int kk = item >> 3, dq = (item & 7) << 2;
        float4 v = {0, 0, 0, 0};
        if (kk < 300)
            v = *(const float4*)(qkv + (size_t)(b * 300 + kk) * 768 + 512 + h * 32 + dq);
        Vt[(dq + 0) * 328 + kk] = f2bf(v.x);
        Vt[(dq + 1) * 328 + kk] = f2bf(v.y);
        Vt[(dq + 2) * 328 + kk] = f2bf(v.z);
        Vt[(dq + 3) * 328 + kk] = f2bf(v.w);
    }
    // ---- Q A-fragment from global (scaled) ----
    short8 qf;
    {
        int qrow = q0 + 16 * wv + c15; if (qrow > 299) qrow = 299;
        const float* qs = qkv + (size_t)(b * 300 + qrow) * 768 + h * 32 + (slot << 3);
        float4 a0 = *(const float4*)qs, a1 = *(const float4*)(qs + 4);
        qf[0] = (short)f2bf(a0.x * scale); qf[1] = (short)f2bf(a0.y * scale);
        qf[2] = (short)f2bf(a0.z * scale); qf[3] = (short)f2bf(a0.w * scale);
        qf[4] = (short)f2bf(a1.x * scale); qf[5] = (short)f2bf(a1.y * scale);
        qf[6] = (short)f2bf(a1.z * scale); qf[7] = (short)f2bf(a1.w * scale);
    }
    __syncthreads();

    // ---- QK^T: 19 k-tiles of 16, scores in registers ----
    f32x4 sc[19];
    const f32x4 zero4 = {0.f, 0.f, 0.f, 0.f};
#pragma unroll
    for (int t = 0; t < 19; t++) {
        short8 kf = *(const short8*)(Ksh + (16 * t + c15) * 40 + (slot << 3));
        sc[t] = __builtin_amdgcn_mfma_f32_16x16x32_bf16(qf, kf, zero4, 0, 0, 0);
    }
    __syncthreads();   // K dead everywhere; P may now overwrite it

    // ---- in-register softmax; P -> LDS bf16 ----
    float linv[4];
    const int prow0 = 16 * wv + (slot << 2);
#pragma unroll
    for (int e = 0; e < 4; e++) {
        float mm = -1e30f;
#pragma unroll
        for (int t = 0; t < 18; t++) mm = fmaxf(mm, sc[t][e]);
        if (c15 < 12) mm = fmaxf(mm, sc[18][e]);
        mm = fmaxf(mm, __shfl_xor(mm, 1));
        mm = fmaxf(mm, __shfl_xor(mm, 2));
        mm = fmaxf(mm, __shfl_xor(mm, 4));
        mm = fmaxf(mm, __shfl_xor(mm, 8));
        float ls = 0.f;
#pragma unroll
        for (int t = 0; t < 19; t++) {
            float p = __expf(sc[t][e] - mm);
            if (t == 18 && c15 >= 12) p = 0.f;
            ls += p;
            Psh[(prow0 + e) * 328 + 16 * t + c15] = f2bf(p);
        }
        ls += __shfl_xor(ls, 1);
        ls += __shfl_xor(ls, 2);
        ls += __shfl_xor(ls, 4);
        ls += __shfl_xor(ls, 8);
        linv[e] = 1.f / ls;
    }
    // zero P cols 304..319 of this wave's rows (PV k-steps reach 319)
    {
        int r = 16 * wv + (l >> 2);
        int c = 304 + ((l & 3) << 2);
        Psh[r * 328 + c + 0] = 0; Psh[r * 328 + c + 1] = 0;
        Psh[r * 328 + c + 2] = 0; Psh[r * 328 + c + 3] = 0;
    }

    // ---- PV: O[16q x 32d] per wave, 10 k-steps of 32 ----
#pragma unroll
    for (int df = 0; df < 2; df++) {
        f32x4 o = zero4;
#pragma unroll
        for (int t = 0; t < 10; t++) {
            short8 pf = *(const short8*)(Psh + (16 * wv + c15) * 328 + 32 * t + (slot << 3));
            short8 vf = *(const short8*)(Vt + (16 * df + c15) * 328 + 32 * t + (slot << 3));
            o = __builtin_amdgcn_mfma_f32_16x16x32_bf16(pf, vf, o, 0, 0, 0);
        }
#pragma unroll
        for (int e = 0; e < 4; e++) {
            int qrow = q0 + prow0 + e;
            if (qrow < 300)
                outp[(size_t)(b * 300 + qrow) * 256 + h * 32 + 16 * df + c15] = o[e] * linv[e];
        }
    }
}

// ---------- LayerNorm: one wave per row of 256 ----------
__global__ __launch_bounds__(256) void k_ln(const float* __restrict__ x, const float* __restrict__ g,
                                            const float* __restrict__ bb, float* __restrict__ out, int M)
{
    int row = blockIdx.x * 4 + (threadIdx.x >> 6);
    int lane = threadIdx.x & 63;
    if (row >= M) return;
    const float* xr = x + (size_t)row * 256;
    float4 v = *(const float4*)(xr + lane * 4);
    float s  = v.x + v.y + v.z + v.w;
    float s2 = v.x*v.x + v.y*v.y + v.z*v.z + v.w*v.w;
#pragma unroll
    for (int off = 32; off >= 1; off >>= 1) {
        s  += __shfl_xor(s, off);
        s2 += __shfl_xor(s2, off);
    }
    float m   = s * 0.00390625f;
    float var = s2 * 0.00390625f - m * m;
    float r   = rsqrtf(var + 1e-5f);
    float4 gv = *(const float4*)(g + lane * 4);
    float4 bv = *(const float4*)(bb + lane * 4);
    float4 o;
    o.x = (v.x - m) * r * gv.x + bv.x;
    o.y = (v.y - m) * r * gv.y + bv.y;
    o.z = (v.z - m) * r * gv.z + bv.z;
    o.w = (v.w - m) * r * gv.w + bv.w;
    *(float4*)(out + (size_t)row * 256 + lane * 4) = o;
}

// ---------- deformable sampling with inline aw-softmax ----------
__global__ __launch_bounds__(256) void k_msda(const u16* __restrict__ value, const float* __restrict__ offaw,
                                              const float* __restrict__ ref, float* __restrict__ samp)
{
    int it = blockIdx.x * 8 + (threadIdx.x >> 5);
    int d  = threadIdx.x & 31;
    int h = it & 7, row = it >> 3;
    int b = row / 300;
    const float* rf = ref + (size_t)row * 4;
    float rx = rf[0], ry = rf[1];
    float rw = rf[2] * 0.125f, rh = rf[3] * 0.125f;   // /P * 0.5
    const float* offp = offaw + (size_t)row * 288 + h * 24;
    const float* awp  = offaw + (size_t)row * 288 + 192 + h * 12;
    // inline softmax over 12 (redundant per lane, VALU-cheap)
    float aw[12];
    {
        float mm = awp[0];
#pragma unroll
        for (int i = 1; i < 12; i++) mm = fmaxf(mm, awp[i]);
        float ssum = 0.f;
#pragma unroll
        for (int i = 0; i < 12; i++) { aw[i] = __expf(awp[i] - mm); ssum += aw[i]; }
        float inv = 1.f / ssum;
#pragma unroll
        for (int i = 0; i < 12; i++) aw[i] *= inv;
    }
    const u16* vb = value + ((size_t)(b * 8 + h)) * 8400 * 32 + d;
    const int HW[3] = {80, 40, 20};
    const int st[3] = {0, 6400, 8000};
    float acc = 0.f;
#pragma unroll
    for (int lv = 0; lv < 3; lv++) {
        int Wl = HW[lv], Hl = HW[lv];
        float Wf = (float)Wl, Hf = (float)Hl;
#pragma unroll
        for (int p = 0; p < 4; p++) {
            float a = aw[lv * 4 + p];
            float x = (rx + offp[lv*8 + p*2]     * rw) * Wf - 0.5f;
            float y = (ry + offp[lv*8 + p*2 + 1] * rh) * Hf - 0.5f;
            float xf = floorf(x), yf = floorf(y);
            float wx = x - xf, wy = y - yf;
            int x0 = (int)xf, y0 = (int)yf;
#pragma unroll
            for (int t = 0; t < 4; t++) {
                int xx = x0 + (t & 1), yy = y0 + (t >> 1);
                if (xx >= 0 && xx < Wl && yy >= 0 && yy < Hl) {
                    float w = ((t & 1) ? wx : 1.f - wx) * ((t >> 1) ? wy : 1.f - wy);
                    acc += a * w * bf2f(vb[(size_t)(st[lv] + yy * Wl + xx) * 32]);
                }
            }
        }
    }
    samp[(size_t)row * 256 + h * 32 + d] = acc;
}

// ---------- qpe hidden: relu(ref(4) @ W1(4,512) + b1) ----------
__global__ void k_qpe_hidden(const float* __restrict__ ref, const float* __restrict__ W1,
                             const float* __restrict__ b1, float* __restrict__ hid)
{
    int idx = blockIdx.x * 256 + threadIdx.x;
    if (idx >= 4800 * 512) return;
    int row = idx >> 9, col = idx & 511;
    const float* r = ref + (size_t)row * 4;
    float v = b1[col] + r[0]*W1[col] + r[1]*W1[512+col] + r[2]*W1[1024+col] + r[3]*W1[1536+col];
    hid[idx] = fmaxf(v, 0.f);
}

// ---------- bbox tail ----------
__global__ __launch_bounds__(64) void k_bb3(const float* __restrict__ bb2, const float* __restrict__ W3,
                                            const float* __restrict__ b3, float* __restrict__ ref)
{
    int row = blockIdx.x;
    int lane = threadIdx.x;
    const float* xr = bb2 + (size_t)row * 256;
    float s0 = 0, s1 = 0, s2 = 0, s3 = 0;
#pragma unroll
    for (int k = lane; k < 256; k += 64) {
        float xv = xr[k];
        float4 w = *(const float4*)(W3 + k * 4);
        s0 += xv * w.x; s1 += xv * w.y; s2 += xv * w.z; s3 += xv * w.w;
    }
#pragma unroll
    for (int off = 32; off >= 1; off >>= 1) {
        s0 += __shfl_xor(s0, off); s1 += __shfl_xor(s1, off);
        s2 += __shfl_xor(s2, off); s3 += __shfl_xor(s3, off);
    }
    if (lane == 0) {
        float sv[4] = {s0, s1, s2, s3};
        float* rr = ref + (size_t)row * 4;
#pragma unroll
        for (int j = 0; j < 4; j++) {
            float v = sv[j] + b3[j];
            float o = rr[j];
            o = fminf(fmaxf(o, 1e-5f), 1.f - 1e-5f);
            float inv = logf(o / (1.f - o));
            rr[j] = 1.f / (1.f + expf(-(v + inv)));
        }
    }
}

// ---------- small utility kernels ----------
__global__ void k_cvt_bf16(const float* __restrict__ in, u16* __restrict__ out, int n4)
{
    int i = blockIdx.x * 256 + threadIdx.x;
    if (i >= n4) return;
    float4 v = ((const float4*)in)[i];
    ushort4 h; h.x = f2bf(v.x); h.y = f2bf(v.y); h.z = f2bf(v.z); h.w = f2bf(v.w);
    ((ushort4*)out)[i] = h;
}
__global__ void k_copy4(const float* __restrict__ in, float* __restrict__ out, int n4)
{
    int i = blockIdx.x * 256 + threadIdx.x;
    if (i >= n4) return;
    ((float4*)out)[i] = ((const float4*)in)[i];
}
__global__ void k_sigmoid(const float* __restrict__ in, float* __restrict__ out, int n)
{
    int i = blockIdx.x * 256 + threadIdx.x;
    if (i >= n) return;
    out[i] = 1.f / (1.f + __expf(-in[i]));
}

// ---------- host-side launch helpers ----------
static inline dim3 g32(int M, int N) { return dim3((M + 31) / 32, (N + 127) / 128); }

static void gemm_plain(const float* A, const u16* Bt, const float* bias, float* C,
                       int M, int N, int K, hipStream_t s) {
    k_gemm<32, 0, 0, false, false><<<g32(M, N), 256, 0, s>>>((const void*)A, nullptr, Bt, bias, nullptr, (void*)C, M, N, K);
}
static void gemm_add(const float* A, const float* A2, const u16* Bt, const float* bias, float* C,
                     int M, int N, int K, hipStream_t s) {
    k_gemm<32, 1, 0, false, false><<<g32(M, N), 256, 0, s>>>((const void*)A, A2, Bt, bias, nullptr, (void*)C, M, N, K);
}
static void gemm_qkv(const float* A, const float* A2, const u16* Bt, const float* bias, float* C,
                     hipStream_t s) {
    k_gemm<32, 3, 0, false, false><<<g32(4800, 768), 256, 0, s>>>((const void*)A, A2, Bt, bias, nullptr, (void*)C, 4800, 768, 256);
}
static void gemm_resid(const float* A, const u16* Bt, const float* bias, const float* resid, float* C,
                       int M, int N, int K, hipStream_t s) {
    k_gemm<32, 0, 0, false, true><<<g32(M, N), 256, 0, s>>>((const void*)A, nullptr, Bt, bias, resid, (void*)C, M, N, K);
}
static void gemm_relu(const float* A, const u16* Bt, const float* bias, float* C,
                      int M, int N, int K, hipStream_t s) {
    k_gemm<32, 0, 0, true, false><<<g32(M, N), 256, 0, s>>>((const void*)A, nullptr, Bt, bias, nullptr, (void*)C, M, N, K);
}
static void gemm_value(const u16* A, const u16* Bt, const float* bias, u16* C, hipStream_t s) {
    k_gemm<128, 2, 1, false, false><<<dim3(1050, 2), 256, 0, s>>>((const void*)A, nullptr, Bt, bias, nullptr, (void*)C, 134400, 256, 256);
}

extern "C" void kernel_launch(void* const* d_in, const int* in_sizes, int n_in,
                              void* d_out, int out_size, void* d_ws, size_t ws_size,
                              hipStream_t stream)
{
    const float* tgt       = (const float*)d_in[0];
    const float* ref_unact = (const float*)d_in[1];
    const float* memory    = (const float*)d_in[2];
    const float* self_Wq = (const float*)d_in[4];
    const float* self_bq = (const float*)d_in[5];
    const float* self_Wk = (const float*)d_in[6];
    const float* self_bk = (const float*)d_in[7];
    const float* self_Wv = (const float*)d_in[8];
    const float* self_bv = (const float*)d_in[9];
    const float* self_Wo = (const float*)d_in[10];
    const float* self_bo = (const float*)d_in[11];
    const float* ln1_g = (const float*)d_in[12];
    const float* ln1_b = (const float*)d_in[13];
    const float* ln2_g = (const float*)d_in[14];
    const float* ln2_b = (const float*)d_in[15];
    const float* ln3_g = (const float*)d_in[16];
    const float* ln3_b = (const float*)d_in[17];
    const float* off_W = (const float*)d_in[18];
    const float* off_b = (const float*)d_in[19];
    const float* aw_W  = (const float*)d_in[20];
    const float* aw_b  = (const float*)d_in[21];
    const float* val_W = (const float*)d_in[22];
    const float* val_b = (const float*)d_in[23];
    const float* out_W = (const float*)d_in[24];
    const float* out_b = (const float*)d_in[25];
    const float* ffn_W1 = (const float*)d_in[26];
    const float* ffn_b1 = (const float*)d_in[27];
    const float* ffn_W2 = (const float*)d_in[28];
    const float* ffn_b2 = (const float*)d_in[29];
    const float* qph_W1 = (const float*)d_in[30];
    const float* qph_b1 = (const float*)d_in[31];
    const float* qph_W2 = (const float*)d_in[32];
    const float* qph_b2 = (const float*)d_in[33];
    const float* bb_W1 = (const float*)d_in[34];
    const float* bb_b1 = (const float*)d_in[35];
    const float* bb_W2 = (const float*)d_in[36];
    const float* bb_b2 = (const float*)d_in[37];
    const float* bb_W3 = (const float*)d_in[38];
    const float* bb_b3 = (const float*)d_in[39];
    const float* sc_W  = (const float*)d_in[40];
    const float* sc_b  = (const float*)d_in[41];
    float* out_f = (float*)d_out;

    // ---- workspace layout (bytes) ----
    char* w = (char*)d_ws;
    u16* mem_bf = (u16*)(w + 0);                // 68,812,800 B
    u16* value  = (u16*)(w + 68812800);         // 68,812,800 B
    const size_t F0 = 137625600;
    float* ws_out   = (float*)(w + F0);                 // 4800x256
    float* ws_qpe   = (float*)(w + F0 +  4915200);      // 4800x256
    float* ws_hid   = (float*)(w + F0 +  9830400);      // 4800x512
    float* ws_qkv   = (float*)(w + F0 + 19660800);      // 4800x768 (Q|K|V)
    float* ws_attn  = (float*)(w + F0 + 34406400);      // 4800x256
    float* ws_offaw = (float*)(w + F0 + 39321600);      // 4800x288 (off|aw raw)
    float* ws_samp  = (float*)(w + F0 + 44851200);      // 4800x256
    float* ws_ffn   = (float*)(w + F0 + 49766400);      // 4800x1024
    float* ws_bb1   = (float*)(w + F0 + 69427200);      // 4800x256
    float* ws_bb2   = (float*)(w + F0 + 74342400);      // 4800x256
    float* ws_ref   = (float*)(w + F0 + 79257600);      // 4800x4
    float* bias_qkv = (float*)(w + F0 + 79334400);      // 6x768
    float* bias_oa  = (float*)(w + F0 + 79352832);      // 6x288
    // ---- bf16 transposed weights (u16 elements), 16B-aligned ----
    u16* wt = (u16*)(w + F0 + 79360000);
    u16* wt_qkv   = wt;                    // 6 x 768x256
    u16* wt_o     = wt_qkv   + 1179648;    // 6 x 65536
    u16* wt_offaw = wt_o     + 393216;     // 6 x 288x256
    u16* wt_val   = wt_offaw + 442368;
    u16* wt_out   = wt_val   + 393216;
    u16* wt_f1    = wt_out   + 393216;     // 6 x 262144
    u16* wt_f2    = wt_f1    + 1572864;
    u16* wt_b1    = wt_f2    + 1572864;
    u16* wt_b2    = wt_b1    + 393216;
    u16* wt_qp2   = wt_b2    + 393216;     // 131072
    u16* wt_sc    = wt_qp2   + 131072;     // 20480
    // scratch for resid->LN round trip, after weights (16B aligned)
    float* ws_tmp   = (float*)(w + F0 + 79360000 + 13770752);  // 4800x256

    // ---- init: weight transposes + bias packs ----
    k_wt<<<dim3(8, 8, 6),  256, 0, stream>>>(self_Wq, wt_qkv,           256, 256, 196608);
    k_wt<<<dim3(8, 8, 6),  256, 0, stream>>>(self_Wk, wt_qkv + 65536,   256, 256, 196608);
    k_wt<<<dim3(8, 8, 6),  256, 0, stream>>>(self_Wv, wt_qkv + 131072,  256, 256, 196608);
    k_wt<<<dim3(8, 8, 6),  256, 0, stream>>>(self_Wo, wt_o,             256, 256, 65536);
    k_wt<<<dim3(8, 6, 6),  256, 0, stream>>>(off_W,   wt_offaw,         256, 192, 73728);
    k_wt<<<dim3(8, 3, 6),  256, 0, stream>>>(aw_W,    wt_offaw + 49152, 256, 96,  73728);
    k_wt<<<dim3(8, 8, 6),  256, 0, stream>>>(val_W,   wt_val,           256, 256, 65536);
    k_wt<<<dim3(8, 8, 6),  256, 0, stream>>>(out_W,   wt_out,           256, 256, 65536);
    k_wt<<<dim3(8, 32, 6), 256, 0, stream>>>(ffn_W1,  wt_f1,            256, 1024, 262144);
    k_wt<<<dim3(32, 8, 6), 256, 0, stream>>>(ffn_W2,  wt_f2,            1024, 256, 262144);
    k_wt<<<dim3(8, 8, 6),  256, 0, stream>>>(bb_W1,   wt_b1,            256, 256, 65536);
    k_wt<<<dim3(8, 8, 6),  256, 0, stream>>>(bb_W2,   wt_b2,            256, 256, 65536);
    k_wt<<<dim3(16, 8, 1), 256, 0, stream>>>(qph_W2,  wt_qp2,           512, 256, 131072);
    k_wt<<<dim3(8, 3, 1),  256, 0, stream>>>(sc_W + (size_t)5 * 20480, wt_sc, 256, 80, 20480);
    k_packb<<<dim3(1, 1, 6), 256, 0, stream>>>(self_bq, 256, bias_qkv, 0,   768);
    k_packb<<<dim3(1, 1, 6), 256, 0, stream>>>(self_bk, 256, bias_qkv, 256, 768);
    k_packb<<<dim3(1, 1, 6), 256, 0, stream>>>(self_bv, 256, bias_qkv, 512, 768);
    k_packb<<<dim3(1, 1, 6), 256, 0, stream>>>(off_b,   192, bias_oa,  0,   288);
    k_packb<<<dim3(1, 1, 6), 256, 0, stream>>>(aw_b,     96, bias_oa,  192, 288);

    k_cvt_bf16<<<33600, 256, 0, stream>>>(memory, mem_bf, 8601600);
    k_copy4   <<<1200,  256, 0, stream>>>(tgt, ws_out, 307200);
    k_sigmoid <<<75,    256, 0, stream>>>(ref_unact, ws_ref, 19200);

    for (int l = 0; l < 6; l++) {
        // qpe = relu(ref @ qph_W1 + b1) @ qph_W2 + b2
        k_qpe_hidden<<<9600, 256, 0, stream>>>(ws_ref, qph_W1, qph_b1, ws_hid);
        gemm_plain(ws_hid, wt_qp2, qph_b2, ws_qpe, 4800, 256, 512, stream);

        // self-attention: fused QKV projection (qpe added only to Q,K tiles)
        gemm_qkv(ws_out, ws_qpe, wt_qkv + (size_t)l * 196608, bias_qkv + l * 768, ws_qkv, stream);
        k_mha3<<<dim3(5, 128), 256, 0, stream>>>(ws_qkv, ws_attn);
        gemm_resid(ws_attn, wt_o + (size_t)l * 65536, self_bo + l * 256, ws_out, ws_tmp, 4800, 256, 256, stream);
        k_ln<<<1200, 256, 0, stream>>>(ws_tmp, ln1_g + l * 256, ln1_b + l * 256, ws_out, 4800);

        // value projection (bf16 A, bf16 out, (b,h,pix,hd) layout)
        gemm_value(mem_bf, wt_val + (size_t)l * 65536, val_b + l * 256, value, stream);

        // deformable attention (fused off|aw projection, softmax inside msda)
        gemm_add(ws_out, ws_qpe, wt_offaw + (size_t)l * 73728, bias_oa + l * 288, ws_offaw, 4800, 288, 256, stream);
        k_msda<<<4800, 256, 0, stream>>>(value, ws_offaw, ws_ref, ws_samp);
        gemm_resid(ws_samp, wt_out + (size_t)l * 65536, out_b + l * 256, ws_out, ws_tmp, 4800, 256, 256, stream);
        k_ln<<<1200, 256, 0, stream>>>(ws_tmp, ln2_g + l * 256, ln2_b + l * 256, ws_out, 4800);

        // FFN
        gemm_relu(ws_out, wt_f1 + (size_t)l * 262144, ffn_b1 + l * 1024, ws_ffn, 4800, 1024, 256, stream);
        gemm_resid(ws_ffn, wt_f2 + (size_t)l * 262144, ffn_b2 + l * 256, ws_out, ws_tmp, 4800, 256, 1024, stream);
        k_ln<<<1200, 256, 0, stream>>>(ws_tmp, ln3_g + l * 256, ln3_b + l * 256, ws_out, 4800);

        // bbox head + ref update
        gemm_relu(ws_out, wt_b1 + (size_t)l * 65536, bb_b1 + l * 256, ws_bb1, 4800, 256, 256, stream);
        gemm_relu(ws_bb1, wt_b2 + (size_t)l * 65536, bb_b2 + l * 256, ws_bb2, 4800, 256, 256, stream);
        k_bb3<<<4800, 64, 0, stream>>>(ws_bb2, bb_W3 + (size_t)l * 1024, bb_b3 + l * 4, ws_ref);
    }

    // outputs: ref (19200 f32) then logits (4800x80 f32)
    k_copy4<<<19, 256, 0, stream>>>(ws_ref, out_f, 4800);
    gemm_plain(ws_out, wt_sc, sc_b + 5 * 80, out_f + 19200, 4800, 80, 256, stream);
}